// Round 9
// baseline (1074.780 us; speedup 1.0000x reference)
//
#include <hip/hip_runtime.h>
#include <cmath>

#define HH 542
#define KH 271
#define NPIX (HH*HH)          // 293764 logical pixels
#define RS 544                // padded fp32 row stride (R0)
#define PPIX (HH*RS)
#define BB 8
#define CC3 3
#define NCH (BB*CC3)
#define NP 12                 // 12 packed complex planes
#define MROWS (NP*HH)         // 6504 complex rows per pass
#define KSZ 31
#define KRAD 15
#define NF 8
#define FS 3

// split-bf16 global format: plane {hi,lo} x [SROWS_PL rows][SROW shorts]
// complex row R, sample s: row = 2R + (s&1), shorts [s&~1, (s&~1)+1] = (re,im)
#define SROW 544              // shorts per split row (542 + 2 pad, 1088 B = 64B-aligned)
#define SROWS_PL 13056        // 2*MROWS = 13008, padded to 13056 for OOB-read slack
#define SPL ((size_t)SROWS_PL*SROW)   // shorts per plane

#define NSPLIT 2
#define NGRP 40               // 20 re + 20 im groups of 16 v1
#define BTSZ (NGRP*NSPLIT*17*512)

typedef __attribute__((ext_vector_type(8))) short short8v;
typedef __attribute__((ext_vector_type(4))) float float4v;

static __device__ __forceinline__ float2 cmul(float2 a, float2 b) {
    return make_float2(a.x*b.x - a.y*b.y, a.x*b.y + a.y*b.x);
}

static __device__ __forceinline__ void pair_chans(int p, int& n1, int& n2) {
    if (p < 8) { n1 = 3*p;     n2 = 3*p + 1; }
    else       { int q = p-8; n1 = 6*q + 2; n2 = 6*q + 5; }
}

// ROUNDED 2-way bf16 split of two values packed as (lo-short=x_hi, hi-short=y_hi).
static __device__ __forceinline__ void split2_pack_pair(float x, float y,
        unsigned& p0, unsigned& p1) {
    unsigned ux = __float_as_uint(x), uy = __float_as_uint(y);
    unsigned hx0 = (ux + 0x8000u) & 0xffff0000u;
    unsigned hy0 = (uy + 0x8000u) & 0xffff0000u;
    float rx = x - __uint_as_float(hx0);
    float ry = y - __uint_as_float(hy0);
    unsigned hx1 = (__float_as_uint(rx) + 0x8000u) & 0xffff0000u;
    unsigned hy1 = (__float_as_uint(ry) + 0x8000u) & 0xffff0000u;
    p0 = (hx0 >> 16) | hy0;
    p1 = (hx1 >> 16) | hy1;
}

// reconstruct (x,y) from hi/lo packed words
static __device__ __forceinline__ float2 unsplit_pair(unsigned h, unsigned l) {
    float x = __uint_as_float(h << 16) + __uint_as_float(l << 16);
    float y = __uint_as_float(h & 0xffff0000u) + __uint_as_float(l & 0xffff0000u);
    return make_float2(x, y);
}

// ---------------- tables: tw542 + fragment-ordered rounded-2-split bf16 B tables.
__global__ void gen_tables(float2* tw542, short* Btf, short* Bti) {
    int idx = blockIdx.x*blockDim.x + threadIdx.x;
    const float PI2 = 6.283185307179586f;
    if (idx < HH) {
        float ang = -PI2*(float)idx/(float)HH;
        float s, c; sincosf(ang, &s, &c);
        tw542[idx] = make_float2(c, s);
    }
    if (idx >= BTSZ) return;
    int j    = idx & 7;
    int lane = (idx >> 3) & 63;
    int rem  = idx >> 9;
    int step = rem % 17;
    int rem2 = rem / 17;
    int s    = rem2 % NSPLIT;
    int g    = rem2 / NSPLIT;
    if (g >= NGRP) return;
    int o  = (g >= 20) ? 1 : 0;
    int v1 = (g - 20*o)*16 + (lane & 15);
    int kq = step*32 + (lane >> 4)*8 + j;
    int kidx = kq >> 1, c = kq & 1;
    float wre = 0.f, wim = 0.f;
    if (v1 < KH && kidx < KH) {
        int r = (kidx*v1) % KH;
        float ang = -PI2*(float)r/(float)KH;
        float sn, cs; sincosf(ang, &sn, &cs);
        wre = cs; wim = sn;
    }
    float vf = (o==0) ? ((c==0) ? wre : -wim) : ((c==0) ?  wim : wre);
    float vi = (o==0) ? ((c==0) ? wre :  wim) : ((c==0) ? -wim : wre);
    {
        unsigned u = __float_as_uint(vf);
        unsigned h0 = (u + 0x8000u) & 0xffff0000u;
        float r1 = vf - __uint_as_float(h0);
        unsigned h1 = (__float_as_uint(r1) + 0x8000u) & 0xffff0000u;
        Btf[idx] = (short)(((s==0) ? h0 : h1) >> 16);
    }
    {
        unsigned u = __float_as_uint(vi);
        unsigned h0 = (u + 0x8000u) & 0xffff0000u;
        float r1 = vi - __uint_as_float(h0);
        unsigned h1 = (__float_as_uint(r1) + 0x8000u) & 0xffff0000u;
        Bti[idx] = (short)(((s==0) ? h0 : h1) >> 16);
    }
}

// ---------------- edgetaper alpha vectors (closed-form autocorrelation)
__global__ void alpha_kernel(const float* __restrict__ kk, float* __restrict__ valpha) {
    int b = blockIdx.x;
    int t = threadIdx.x;
    __shared__ float proj[2][KSZ];
    __shared__ float ac[2][KSZ];
    const float* kb = kk + b*KSZ*KSZ;
    if (t < KSZ) {
        float s = 0;
        for (int j = 0; j < KSZ; j++) s += kb[t*KSZ + j];
        proj[0][t] = s;
    } else if (t >= 32 && t < 32+KSZ) {
        int j = t - 32;
        float s = 0;
        for (int i = 0; i < KSZ; i++) s += kb[i*KSZ + j];
        proj[1][j] = s;
    }
    __syncthreads();
    if (t < KSZ) {
        float s0 = 0, s1 = 0;
        for (int m = 0; m + t < KSZ; m++) {
            s0 += proj[0][m]*proj[0][m+t];
            s1 += proj[1][m]*proj[1][m+t];
        }
        ac[0][t] = s0; ac[1][t] = s1;
    }
    __syncthreads();
    float inv0 = 1.0f/ac[0][0];
    float inv1 = 1.0f/ac[1][0];
    for (int d = t; d < HH; d += blockDim.x) {
        for (int a = 0; a < 2; a++) {
            float z;
            if (d <= 30)                   z = ac[a][d];
            else if (d >= 511 && d <= 540) z = ac[a][541-d];
            else if (d == 541)             z = ac[a][0];
            else                           z = 0.0f;
            valpha[(b*2 + a)*HH + d] = 1.0f - z*(a ? inv1 : inv0);
        }
    }
}

// ---------------- Dk = psf2otf(k) via two small DFT stages (rotation recurrence)
__global__ void dk_stage1(const float* __restrict__ kk, const float2* __restrict__ tw,
                          float2* __restrict__ T1) {
    int idx = blockIdx.x*blockDim.x + threadIdx.x;
    if (idx >= BB*KSZ*HH) return;
    int v  = idx % HH;
    int bm = idx / HH;
    int m  = bm % KSZ;
    int b  = bm / KSZ;
    const float* kb = kk + (b*KSZ + m)*KSZ;
    float2 w  = tw[(KRAD*(HH - v)) % HH];
    float2 ru = tw[v];
    float2 acc = make_float2(0.f, 0.f);
    for (int n = 0; n < KSZ; n++) {
        float kv = kb[n];
        acc.x = fmaf(kv, w.x, acc.x);
        acc.y = fmaf(kv, w.y, acc.y);
        float wx = w.x*ru.x - w.y*ru.y;
        float wy = w.x*ru.y + w.y*ru.x;
        w = make_float2(wx, wy);
    }
    T1[idx] = acc;
}

#define UT2 8
__global__ void dk_stage2(const float2* __restrict__ T1, const float2* __restrict__ tw,
                          float2* __restrict__ Dk) {
    int bid = blockIdx.x;
    int vc = bid % 3;
    int rem = bid / 3;
    int ut = rem % 68;
    int b  = rem / 68;
    int v = vc*256 + threadIdx.x;
    if (v >= HH) return;
    int u0 = ut*UT2;
    float2 acc[UT2], w[UT2], ru[UT2];
    #pragma unroll
    for (int uu = 0; uu < UT2; uu++) {
        int u = u0 + uu;
        int uc = (u < HH) ? u : 0;
        acc[uu] = make_float2(0.f, 0.f);
        w[uu]  = tw[(KRAD*(HH - uc)) % HH];
        ru[uu] = tw[uc];
    }
    const float2* t1 = T1 + (size_t)b*KSZ*HH + v;
    for (int m = 0; m < KSZ; m++) {
        float2 t = t1[(size_t)m*HH];
        #pragma unroll
        for (int uu = 0; uu < UT2; uu++) {
            acc[uu].x = fmaf(t.x, w[uu].x, fmaf(-t.y, w[uu].y, acc[uu].x));
            acc[uu].y = fmaf(t.x, w[uu].y, fmaf( t.y, w[uu].x, acc[uu].y));
            float wx = w[uu].x*ru[uu].x - w[uu].y*ru[uu].y;
            float wy = w[uu].x*ru[uu].y + w[uu].y*ru[uu].x;
            w[uu] = make_float2(wx, wy);
        }
    }
    #pragma unroll
    for (int uu = 0; uu < UT2; uu++) {
        int u = u0 + uu;
        if (u < HH) Dk[(size_t)b*NPIX + (size_t)u*HH + v] = acc[uu];
    }
}

// ---------------- Dg_sum
__global__ void dgs_kernel(const float* __restrict__ filt, const float* __restrict__ lamp,
                           const float2* __restrict__ tw, float* __restrict__ Dgs) {
    int uv = blockIdx.x*blockDim.x + threadIdx.x;
    if (uv >= NPIX) return;
    int u = uv / HH;
    int v = uv - u*HH;
    float el = expf(lamp[0]);
    float2 wu[3], wv[3];
    wu[0] = tw[u ? HH-u : 0]; wu[1] = make_float2(1.f,0.f); wu[2] = tw[u];
    wv[0] = tw[v ? HH-v : 0]; wv[1] = make_float2(1.f,0.f); wv[2] = tw[v];
    float2 ph[3][3];
    #pragma unroll
    for (int m = 0; m < 3; m++)
        #pragma unroll
        for (int n = 0; n < 3; n++)
            ph[m][n] = cmul(wu[m], wv[n]);
    for (int c = 0; c < CC3; c++) {
        float s = 0.f;
        for (int f = 0; f < NF; f++) {
            float2 acc = make_float2(0.f, 0.f);
            const float* fp = filt + ((f*CC3 + c)*FS)*FS;
            #pragma unroll
            for (int m = 0; m < 3; m++)
                #pragma unroll
                for (int n = 0; n < 3; n++) {
                    float fv = fp[m*3+n];
                    acc.x = fmaf(fv, ph[m][n].x, acc.x);
                    acc.y = fmaf(fv, ph[m][n].y, acc.y);
                }
            s = fmaf(acc.x, acc.x, fmaf(acc.y, acc.y, s));
        }
        Dgs[c*NPIX + uv] = s*el;
    }
}

// ---------------- edge-replicate pad + pack pairs -> SPLIT format + fp32 R0
__global__ void pad_pack(const float* __restrict__ y, float* __restrict__ R0,
                         short* __restrict__ CAs) {
    int idx = blockIdx.x*blockDim.x + threadIdx.x;
    if (idx >= NP*NPIX) return;
    int uv = idx % NPIX;
    int p  = idx / NPIX;
    int n1, n2; pair_chans(p, n1, n2);
    int i = uv / HH, j = uv - i*HH;
    int yi = min(max(i - KRAD, 0), 511);
    int yj = min(max(j - KRAD, 0), 511);
    int yo = yi*512 + yj;
    float v1 = y[(size_t)n1*262144 + yo];
    float v2 = y[(size_t)n2*262144 + yo];
    R0[(size_t)n1*PPIX + (size_t)i*RS + j] = v1;
    R0[(size_t)n2*PPIX + (size_t)i*RS + j] = v2;
    unsigned hi, lo; split2_pack_pair(v1, v2, hi, lo);
    size_t row = 2*((size_t)p*HH + i) + (size_t)(j & 1);
    size_t col = (size_t)(j & ~1);
    *(unsigned*)(CAs + row*SROW + col)       = hi;
    *(unsigned*)(CAs + SPL + row*SROW + col) = lo;
}

// ---------------- Hermitian unpack, per-channel multiply, repack (SPLIT in/out).
__global__ void specmul(const short* __restrict__ CAs, const float2* __restrict__ Dk,
                        const float* __restrict__ Dgs, short* __restrict__ CBs, int mode) {
    int idx = blockIdx.x*blockDim.x + threadIdx.x;
    if (idx >= NP*NPIX) return;
    int uv = idx % NPIX;
    int p  = idx / NPIX;
    int n1, n2; pair_chans(p, n1, n2);
    int b1 = n1/3, c1 = n1 - 3*b1;
    int b2 = n2/3, c2 = n2 - 3*b2;
    int i = uv / HH, j = uv - i*HH;
    int ni = i ? HH - i : 0;
    int nj = j ? HH - j : 0;
    size_t rz = 2*((size_t)p*HH + i) + (size_t)(j & 1);
    size_t cz = (size_t)(j & ~1);
    size_t rm = 2*((size_t)p*HH + ni) + (size_t)(nj & 1);
    size_t cm = (size_t)(nj & ~1);
    unsigned zh = *(const unsigned*)(CAs + rz*SROW + cz);
    unsigned zl = *(const unsigned*)(CAs + SPL + rz*SROW + cz);
    unsigned mh = *(const unsigned*)(CAs + rm*SROW + cm);
    unsigned ml = *(const unsigned*)(CAs + SPL + rm*SROW + cm);
    float2 Z  = unsplit_pair(zh, zl);
    float2 Zm = unsplit_pair(mh, ml);
    float2 F1 = make_float2(0.5f*(Z.x + Zm.x), 0.5f*(Z.y - Zm.y));
    float2 F2 = make_float2(0.5f*(Z.y + Zm.y), 0.5f*(Zm.x - Z.x));
    float2 d1 = Dk[(size_t)b1*NPIX + uv];
    float2 d2 = Dk[(size_t)b2*NPIX + uv];
    float2 M1, M2;
    if (mode == 0) {
        M1 = d1; M2 = d2;
    } else {
        float o1 = 1.0f/(d1.x*d1.x + d1.y*d1.y + Dgs[(size_t)c1*NPIX + uv]);
        float o2 = 1.0f/(d2.x*d2.x + d2.y*d2.y + Dgs[(size_t)c2*NPIX + uv]);
        M1 = make_float2(d1.x*o1, -d1.y*o1);
        M2 = make_float2(d2.x*o2, -d2.y*o2);
    }
    float2 W1 = cmul(M1, F1);
    float2 W2 = cmul(M2, F2);
    float2 out = make_float2(W1.x - W2.y, W1.y + W2.x);
    unsigned hi, lo; split2_pack_pair(out.x, out.y, hi, lo);
    *(unsigned*)(CBs + rz*SROW + cz)       = hi;
    *(unsigned*)(CBs + SPL + rz*SROW + cz) = lo;
}

// ---------------- MFMA DFT pass, LDS-FREE K-loop.
// A fragments loaded DIRECTLY from the pre-split global format (per-lane
// addresses; layout == old LDS layout lifted to global). No barriers, no
// ds ops, no VALU split in the K-loop: K-loop = 12 loads + 24 MFMA per wave
// per step. Old K-loop was LDS-pipe-bound (~60%: 8 ds_read + 4 ds_write +
// conflicts + 2 barrier drains per step). A reuse: 4KB/step/block hits L1
// (4 waves read identical fragments). Pad shorts/rows are ZEROED by memset
// (B=0 guard kills k'=542/543; OOB rows only affect skipped outputs).
__global__ void __launch_bounds__(256, 4)
fft_mfma(const short* __restrict__ Ains, short* __restrict__ Aouts,
         const short* __restrict__ Bt, const float2* __restrict__ tw542,
         const float* __restrict__ valp, float* __restrict__ R0,
         float* __restrict__ outbuf, float scale, int conjtw, int mode)
{
    __shared__ float4 Tsf[64*17];         // epilogue transpose only (17408 B)

    int id = blockIdx.x;
    int xcd = id & 7, jj = id >> 3;
    int lin = xcd*128 + jj;
    if (lin >= 1020) return;
    int by = lin / 5, bx = lin - 5*by;    // by 0..203 (32-complex-row tiles), bx 0..4

    int tid = threadIdx.x;
    int wid = tid >> 6, lane = tid & 63;
    int l15 = lane & 15, quad = lane >> 4;

    // per-lane A fragment pointers: [split plane][mt] ; k advances via step*32 shorts
    const short* pA[2][4];
    #pragma unroll
    for (int sa = 0; sa < 2; sa++)
        #pragma unroll
        for (int mt = 0; mt < 4; mt++) {
            size_t rl = (size_t)by*64 + (size_t)(l15 + mt*16);   // < SROWS_PL (padded)
            pA[sa][mt] = Ains + (size_t)sa*SPL + rl*SROW + quad*8;
        }

    // per-wave B groups: re = bx*4+wid, im = 20 + bx*4+wid
    const short* pB[2];
    #pragma unroll
    for (int ct = 0; ct < 2; ct++) {
        int grp = (ct ? 20 : 0) + bx*4 + wid;
        pB[ct] = Bt + (size_t)grp*(NSPLIT*17*512) + lane*8;
    }

    float4v acc[4][2];   // [mt][re/im]
    #pragma unroll
    for (int mt = 0; mt < 4; mt++)
        #pragma unroll
        for (int ct = 0; ct < 2; ct++)
            acc[mt][ct] = (float4v)(0.f);

    #pragma unroll 2
    for (int step = 0; step < 17; step++) {
        short8v af[2][4], bfv[2][2];
        #pragma unroll
        for (int sa = 0; sa < 2; sa++)
            #pragma unroll
            for (int mt = 0; mt < 4; mt++)
                af[sa][mt] = *(const short8v*)(pA[sa][mt] + step*32);
        #pragma unroll
        for (int ct = 0; ct < 2; ct++)
            #pragma unroll
            for (int s = 0; s < NSPLIT; s++)
                bfv[ct][s] = *(const short8v*)(pB[ct] + ((s*17 + step) << 9));
        #pragma unroll
        for (int sa = 0; sa < 2; sa++)
            #pragma unroll
            for (int sb = 0; sb + sa < 2; sb++)
                #pragma unroll
                for (int mt = 0; mt < 4; mt++)
                    #pragma unroll
                    for (int ct = 0; ct < 2; ct++)
                        acc[mt][ct] = __builtin_amdgcn_mfma_f32_16x16x32_bf16(
                            af[sa][mt], bfv[ct][sb], acc[mt][ct], 0, 0, 0);
    }

    // ---- epilogue: twiddle combine, LDS transpose (64 v1 x 32 cols), split stores
    float2 tg;
    {
        int v1g = (bx*4 + wid)*16 + l15;
        tg = tw542[(v1g < HH) ? v1g : 0];
        if (conjtw) tg.y = -tg.y;
    }

    int lane16 = tid & 15;
    int rrow = tid >> 4;                  // 0..15
    int r0 = by*32 + 2*lane16;            // even complex col
    bool rok = r0 < MROWS;
    int plane = rok ? (r0 / HH) : 0;
    int colg = r0 - plane*HH;
    int n1, n2; pair_chans(plane, n1, n2);
    int b1 = n1/3, b2 = n2/3;

    #pragma unroll
    for (int half = 0; half < 2; half++) {
        __syncthreads();
        #pragma unroll
        for (int mt = 0; mt < 4; mt++) {
            float2 v[2];
            #pragma unroll
            for (int pr = 0; pr < 2; pr++) {
                float Ere = acc[mt][0][2*pr], Ore = acc[mt][0][2*pr+1];
                float Eim = acc[mt][1][2*pr], Oim = acc[mt][1][2*pr+1];
                float tOre = tg.x*Ore - tg.y*Oim;
                float tOim = tg.x*Oim + tg.y*Ore;
                v[pr] = (half == 0)
                    ? make_float2((Ere + tOre)*scale, (Eim + tOim)*scale)
                    : make_float2((Ere - tOre)*scale, (Eim - tOim)*scale);
            }
            int v1loc = wid*16 + l15;
            int uu = mt*4 + quad;
            Tsf[v1loc*17 + uu] = make_float4(v[0].x, v[0].y, v[1].x, v[1].y);
        }
        __syncthreads();
        #pragma unroll
        for (int it = 0; it < 4; it++) {
            int v1loc = rrow + it*16;
            int v1g2 = bx*64 + v1loc;
            if (v1g2 >= KH || !rok) continue;
            int v1 = v1g2 + (half ? KH : 0);
            float4 f = Tsf[v1loc*17 + lane16];   // samples colg=(x,y), colg+1=(z,w)
            size_t Rout = (size_t)plane*HH + v1; // output complex row
            size_t re = 2*Rout;                  // even-sample split row
            if (mode == 0) {
                unsigned h0,l0,h1,l1;
                split2_pack_pair(f.x, f.y, h0, l0);
                split2_pack_pair(f.z, f.w, h1, l1);
                *(unsigned*)(Aouts + re*SROW + colg)             = h0;
                *(unsigned*)(Aouts + (re+1)*SROW + colg)         = h1;
                *(unsigned*)(Aouts + SPL + re*SROW + colg)       = l0;
                *(unsigned*)(Aouts + SPL + (re+1)*SROW + colg)   = l1;
            } else if (mode == 1) {
                float ar1 = valp[b1*2*HH + v1];
                float ar2 = valp[b2*2*HH + v1];
                float ac1a = valp[(b1*2+1)*HH + colg];
                float ac1b = valp[(b1*2+1)*HH + colg + 1];
                float ac2a = valp[(b2*2+1)*HH + colg];
                float ac2b = valp[(b2*2+1)*HH + colg + 1];
                size_t sp = (size_t)v1*RS + colg;
                float2* p1 = (float2*)(R0 + (size_t)n1*PPIX + sp);
                float2* p2 = (float2*)(R0 + (size_t)n2*PPIX + sp);
                float2 o1 = *p1, o2 = *p2;
                float nv1a = fmaf(ar1*ac1a, o1.x - f.x, f.x);
                float nv1b = fmaf(ar1*ac1b, o1.y - f.z, f.z);
                float nv2a = fmaf(ar2*ac2a, o2.x - f.y, f.y);
                float nv2b = fmaf(ar2*ac2b, o2.y - f.w, f.w);
                *p1 = make_float2(nv1a, nv1b);
                *p2 = make_float2(nv2a, nv2b);
                unsigned h0,l0,h1,l1;
                split2_pack_pair(nv1a, nv2a, h0, l0);   // sample colg
                split2_pack_pair(nv1b, nv2b, h1, l1);   // sample colg+1
                *(unsigned*)(Aouts + re*SROW + colg)             = h0;
                *(unsigned*)(Aouts + (re+1)*SROW + colg)         = h1;
                *(unsigned*)(Aouts + SPL + re*SROW + colg)       = l0;
                *(unsigned*)(Aouts + SPL + (re+1)*SROW + colg)   = l1;
            } else {
                size_t so = (size_t)v1*HH + colg;   // TRUE 542 stride fp32 output
                *(float2*)(outbuf + (size_t)n1*NPIX + so) = make_float2(f.x, f.z);
                *(float2*)(outbuf + (size_t)n2*NPIX + so) = make_float2(f.y, f.w);
            }
        }
    }
}

extern "C" void kernel_launch(void* const* d_in, const int* in_sizes, int n_in,
                              void* d_out, int out_size, void* d_ws, size_t ws_size,
                              hipStream_t stream) {
    const float* y    = (const float*)d_in[0];
    const float* k    = (const float*)d_in[1];
    const float* lam  = (const float*)d_in[2];
    const float* filt = (const float*)d_in[3];
    float* out = (float*)d_out;

    char* base = (char*)d_ws;
    size_t off = 0;
    auto alloc = [&](size_t bytes) {
        void* p = base + off;
        off = (off + bytes + 511) & ~(size_t)511;
        return p;
    };
    short*  CAs  = (short*) alloc(sizeof(short)*2*SPL);
    short*  CBs  = (short*) alloc(sizeof(short)*2*SPL);
    float*  R0   = (float*) alloc(sizeof(float)*(size_t)NCH*PPIX);
    float2* Dk   = (float2*)alloc(sizeof(float2)*(size_t)BB*NPIX);
    float2* T1   = (float2*)alloc(sizeof(float2)*(size_t)BB*KSZ*HH);
    float*  Dgs  = (float*) alloc(sizeof(float)*(size_t)CC3*NPIX);
    short*  Btf  = (short*) alloc(sizeof(short)*(size_t)BTSZ);
    short*  Bti  = (short*) alloc(sizeof(short)*(size_t)BTSZ);
    float2* tw   = (float2*)alloc(sizeof(float2)*(size_t)HH);
    float*  valp = (float*) alloc(sizeof(float)*(size_t)BB*2*HH);
    (void)ws_size; (void)in_sizes; (void)n_in; (void)out_size;

    const int TPB = 256;
    auto nb = [](long n) { return (int)((n + 255)/256); };

    // zero split buffers: pad shorts 542/543 and pad rows must be 0 (never
    // written by any producer; garbage NaN * B=0 would poison accumulators).
    hipMemsetAsync(CAs, 0, sizeof(short)*2*SPL, stream);
    hipMemsetAsync(CBs, 0, sizeof(short)*2*SPL, stream);

    gen_tables<<<nb((long)BTSZ), TPB, 0, stream>>>(tw, Btf, Bti);
    alpha_kernel<<<BB, 64, 0, stream>>>(k, valp);
    dk_stage1<<<nb((long)BB*KSZ*HH), TPB, 0, stream>>>(k, tw, T1);
    dk_stage2<<<8*68*3, TPB, 0, stream>>>(T1, tw, Dk);
    dgs_kernel<<<nb((long)NPIX), TPB, 0, stream>>>(filt, lam, tw, Dgs);
    pad_pack<<<nb((long)NP*NPIX), TPB, 0, stream>>>(y, R0, CAs);

    const int FG = 1024;  // 8 XCDs x 128 (1020 active) -> 4 blocks/CU
    const float isc = 1.0f/(float)HH;
    short *S = CAs, *T = CBs;
    fft_mfma<<<FG, TPB, 0, stream>>>(S, T, Btf, tw, valp, R0, out, 1.0f, 0, 0);
    fft_mfma<<<FG, TPB, 0, stream>>>(T, S, Btf, tw, valp, R0, out, 1.0f, 0, 0);
    for (int it = 0; it < 3; it++) {
        specmul<<<nb((long)NP*NPIX), TPB, 0, stream>>>(S, Dk, Dgs, T, 0);
        fft_mfma<<<FG, TPB, 0, stream>>>(T, S, Bti, tw, valp, R0, out, isc, 1, 0);
        fft_mfma<<<FG, TPB, 0, stream>>>(S, T, Bti, tw, valp, R0, out, isc, 1, 1);
        fft_mfma<<<FG, TPB, 0, stream>>>(T, S, Btf, tw, valp, R0, out, 1.0f, 0, 0);
        fft_mfma<<<FG, TPB, 0, stream>>>(S, T, Btf, tw, valp, R0, out, 1.0f, 0, 0);
        short* tmp = S; S = T; T = tmp;
    }
    specmul<<<nb((long)NP*NPIX), TPB, 0, stream>>>(S, Dk, Dgs, T, 1);
    fft_mfma<<<FG, TPB, 0, stream>>>(T, S, Bti, tw, valp, R0, out, isc, 1, 0);
    fft_mfma<<<FG, TPB, 0, stream>>>(S, T, Bti, tw, valp, R0, out, isc, 1, 2);
}